// Round 1
// baseline (302.164 us; speedup 1.0000x reference)
//
#include <hip/hip_runtime.h>
#include <math.h>

#define KK 64
#define DD 256
#define INV_TAU 2.0f
#define EPSL 1e-8f

// ws float layout:
// [0, K*D)            sum_atac
// [K*D, 2K*D)         sum_rna
// [2K*D, 2K*D+K)      cnt_atac
// [2K*D+K, 2K*D+2K)   cnt_rna
// [2K*D+2K, 3K*D+2K)  A (normalized atac prototypes)
// [3K*D+2K, 4K*D+2K)  R (normalized rna prototypes)
// [4K*D+2K, 4K*D+3K)  loss_k

__global__ __launch_bounds__(256) void seg_sum_kernel(
    const float* __restrict__ fa, const float* __restrict__ fr,
    const int* __restrict__ la, const int* __restrict__ lr,
    float* __restrict__ ws, int N)
{
    __shared__ float acc[KK * DD];
    __shared__ int cnt[KK];
    const int tid = threadIdx.x;
    const int f = blockIdx.y;
    const float* __restrict__ feat = f ? fr : fa;
    const int* __restrict__ label = f ? lr : la;
    float* gsum = ws + (size_t)f * (KK * DD);
    float* gcnt = ws + 2 * KK * DD + f * KK;

    for (int i = tid; i < KK * DD; i += 256) acc[i] = 0.0f;
    if (tid < KK) cnt[tid] = 0;
    __syncthreads();

    const int nb = gridDim.x;
    const int chunk = (N + nb - 1) / nb;
    const int n0 = blockIdx.x * chunk;
    const int n1 = min(N, n0 + chunk);

    int n = n0;
    for (; n + 8 <= n1; n += 8) {
        int l[8];
        float v[8];
        #pragma unroll
        for (int u = 0; u < 8; ++u) l[u] = label[n + u];
        #pragma unroll
        for (int u = 0; u < 8; ++u) v[u] = feat[(size_t)(n + u) * DD + tid];
        #pragma unroll
        for (int u = 0; u < 8; ++u) atomicAdd(&acc[l[u] * DD + tid], v[u]);  // ds_add_f32, no rtn
        if (tid == 0) {
            #pragma unroll
            for (int u = 0; u < 8; ++u) atomicAdd(&cnt[l[u]], 1);
        }
    }
    for (; n < n1; ++n) {
        int l = label[n];
        atomicAdd(&acc[l * DD + tid], feat[(size_t)n * DD + tid]);
        if (tid == 0) atomicAdd(&cnt[l], 1);
    }
    __syncthreads();

    for (int i = tid; i < KK * DD; i += 256) atomicAdd(&gsum[i], acc[i]);
    if (tid < KK) atomicAdd(&gcnt[tid], (float)cnt[tid]);
}

__global__ __launch_bounds__(256) void proto_norm_kernel(float* __restrict__ ws)
{
    const int k = blockIdx.x, tid = threadIdx.x;
    const float* suma = ws;
    const float* sumr = ws + KK * DD;
    const float* cnta = ws + 2 * KK * DD;
    const float* cntr = cnta + KK;
    float* A = ws + 2 * KK * DD + 2 * KK;
    float* R = A + KK * DD;

    float a = suma[k * DD + tid] / cnta[k];
    float r = sumr[k * DD + tid] / cntr[k];
    float sa = a * a, sr = r * r;
    #pragma unroll
    for (int i = 1; i < 64; i <<= 1) {
        sa += __shfl_xor(sa, i, 64);
        sr += __shfl_xor(sr, i, 64);
    }
    __shared__ float redA[4], redR[4];
    const int wid = tid >> 6, lane = tid & 63;
    if (lane == 0) { redA[wid] = sa; redR[wid] = sr; }
    __syncthreads();
    const float na = redA[0] + redA[1] + redA[2] + redA[3];
    const float nr = redR[0] + redR[1] + redR[2] + redR[3];
    A[k * DD + tid] = a / fmaxf(sqrtf(na), 1e-12f);
    R[k * DD + tid] = r / fmaxf(sqrtf(nr), 1e-12f);
}

__global__ __launch_bounds__(256) void loss_kernel(float* __restrict__ ws)
{
    const float* A = ws + 2 * KK * DD + 2 * KK;
    const float* R = A + KK * DD;
    float* lossk = ws + 4 * KK * DD + 2 * KK;
    const int k = blockIdx.x, tid = threadIdx.x;

    const float a = A[k * DD + tid];
    const float r = R[k * DD + tid];
    const float lfp = a * r * INV_TAU;     // log(Fp)
    const float fp = expf(lfp);
    float ssa = 0.0f, ssr = 0.0f;
    #pragma unroll 8
    for (int j = 0; j < KK; ++j) {
        ssa += expf(a * A[j * DD + tid] * INV_TAU);
        ssr += expf(a * R[j * DD + tid] * INV_TAU);
    }
    // Fn = sum_{j!=k} Sa + sum_{j!=k} Sr + 2*(K-1)*Fp
    const float Fn = (ssa - expf(a * a * INV_TAU)) + (ssr - fp) + 2.0f * (KK - 1) * fp;
    float l = logf(Fn + EPSL) - lfp;       // -log(Fp/(Fn+eps))

    #pragma unroll
    for (int i = 1; i < 64; i <<= 1) l += __shfl_xor(l, i, 64);
    __shared__ float red[4];
    const int wid = tid >> 6, lane = tid & 63;
    if (lane == 0) red[wid] = l;
    __syncthreads();
    if (tid == 0) lossk[k] = (red[0] + red[1] + red[2] + red[3]) * (1.0f / DD);
}

__global__ void final_kernel(const float* __restrict__ lossk, float* __restrict__ out)
{
    float v = lossk[threadIdx.x];
    #pragma unroll
    for (int i = 1; i < 64; i <<= 1) v += __shfl_xor(v, i, 64);
    if (threadIdx.x == 0) out[0] = v;
}

extern "C" void kernel_launch(void* const* d_in, const int* in_sizes, int n_in,
                              void* d_out, int out_size, void* d_ws, size_t ws_size,
                              hipStream_t stream)
{
    const float* fa = (const float*)d_in[0];
    const float* fr = (const float*)d_in[1];
    const int* la = (const int*)d_in[2];
    const int* lr = (const int*)d_in[3];
    float* ws = (float*)d_ws;
    float* out = (float*)d_out;
    const int N = in_sizes[2];

    // zero the sum/count accumulator region (ws is NOT re-poisoned between replays)
    hipMemsetAsync(d_ws, 0, (size_t)(2 * KK * DD + 2 * KK) * sizeof(float), stream);

    dim3 g1(256, 2);
    seg_sum_kernel<<<g1, 256, 0, stream>>>(fa, fr, la, lr, ws, N);
    proto_norm_kernel<<<KK, 256, 0, stream>>>(ws);
    loss_kernel<<<KK, 256, 0, stream>>>(ws);
    final_kernel<<<1, 64, 0, stream>>>(ws + 4 * KK * DD + 2 * KK, out);
}